// Round 1
// baseline (309.304 us; speedup 1.0000x reference)
//
#include <hip/hip_runtime.h>
#include <hip/hip_bf16.h>
#include <stdint.h>

typedef __attribute__((ext_vector_type(8))) short bf16x8;
typedef __attribute__((ext_vector_type(4))) float f32x4;

#define DEVFN static __device__ __forceinline__

typedef const __attribute__((address_space(1))) void* gas_ptr;
typedef __attribute__((address_space(3))) void* las_ptr;

// async global->LDS, 16B per lane; LDS dest = wave-uniform base + lane*16
DEVFN void async16(const void* g, void* l) {
  __builtin_amdgcn_global_load_lds((gas_ptr)g, (las_ptr)l, 16, 0, 0);
}

#define S_LEN 2048
#define NH    16
#define HDIM  64
#define KDIM  1024
#define NQKV  3072
#define MTOK  4096

// ---------------- flat cast fp32 -> bf16 ----------------
__global__ void cast_bf16_kernel(const float* __restrict__ in,
                                 __hip_bfloat16* __restrict__ out, int n) {
  int i = (blockIdx.x * 256 + threadIdx.x) * 8;
  if (i >= n) return;
  float4 a = *(const float4*)(in + i);
  float4 b = *(const float4*)(in + i + 4);
  alignas(16) __hip_bfloat16 t[8] = {
      __float2bfloat16(a.x), __float2bfloat16(a.y),
      __float2bfloat16(a.z), __float2bfloat16(a.w),
      __float2bfloat16(b.x), __float2bfloat16(b.y),
      __float2bfloat16(b.z), __float2bfloat16(b.w)};
  *(uint4*)(out + i) = *(const uint4*)t;
}

// ------------- transpose (K,N) fp32 -> (N,K) bf16 -------------
__global__ __launch_bounds__(256) void transpose_cast_kernel(
    const float* __restrict__ in, __hip_bfloat16* __restrict__ out,
    int K, int N) {
  __shared__ float T[64][65];
  const int tid = threadIdx.x;
  const int n0 = blockIdx.x * 64, k0 = blockIdx.y * 64;
#pragma unroll
  for (int it = 0; it < 4; it++) {
    int r = it * 16 + (tid >> 4);
    int c = (tid & 15) * 4;
    float4 v = *(const float4*)&in[(size_t)(k0 + r) * N + n0 + c];
    T[r][c + 0] = v.x; T[r][c + 1] = v.y; T[r][c + 2] = v.z; T[r][c + 3] = v.w;
  }
  __syncthreads();
#pragma unroll
  for (int it = 0; it < 4; it++) {
    int rn = it * 16 + (tid >> 4);
    int ck = (tid & 15) * 4;
    alignas(8) __hip_bfloat16 t4[4];
#pragma unroll
    for (int j = 0; j < 4; j++) t4[j] = __float2bfloat16(T[ck + j][rn]);
    *(ushort4*)&out[(size_t)(n0 + rn) * K + k0 + ck] = *(const ushort4*)t4;
  }
}

// ---------------- QKV GEMM: (4096,1024)x(1024,3072)+bias ----------------
// A row-major bf16, Bt = w_qkv^T (N,K) bf16. Epilogue splits Q/K/V:
//   Q -> q[b][h][s][d] * 0.125 (pre-scaled), K -> k[b][h][s][d], V -> vt[b][h][d][s]
__global__ __launch_bounds__(256, 2) void qkv_gemm_kernel(
    const __hip_bfloat16* __restrict__ A,
    const __hip_bfloat16* __restrict__ Bt,
    const float* __restrict__ bias,
    __hip_bfloat16* __restrict__ qo,
    __hip_bfloat16* __restrict__ ko,
    __hip_bfloat16* __restrict__ vto) {
  __shared__ __hip_bfloat16 As[128 * 32];
  __shared__ __hip_bfloat16 Bs[128 * 32];
  const int tid = threadIdx.x;
  const int wave = tid >> 6, lane = tid & 63;
  const int L = lane & 15, quad = lane >> 4;
  const int wm = wave >> 1, wn = wave & 1;
  const int m0 = blockIdx.y * 128, n0 = blockIdx.x * 128;

  f32x4 acc[4][4] = {};

  const int srow = tid >> 2;
  const int scol = (tid & 3) * 8;
  const __hip_bfloat16* ag = A + (size_t)(m0 + srow) * KDIM + scol;
  const __hip_bfloat16* bg = Bt + (size_t)(n0 + srow) * KDIM + scol;
  char* asd = (char*)As + wave * 1024;
  char* bsd = (char*)Bs + wave * 1024;

  for (int kt = 0; kt < KDIM; kt += 32) {
    async16(ag + kt, asd);
    async16(ag + kt + (size_t)64 * KDIM, asd + 4096);
    async16(bg + kt, bsd);
    async16(bg + kt + (size_t)64 * KDIM, bsd + 4096);
    __syncthreads();  // compiler drains vmcnt before s_barrier
    bf16x8 af[4], bf[4];
#pragma unroll
    for (int r = 0; r < 4; r++)
      af[r] = *(const bf16x8*)&As[(wm * 64 + r * 16 + L) * 32 + quad * 8];
#pragma unroll
    for (int c = 0; c < 4; c++)
      bf[c] = *(const bf16x8*)&Bs[(wn * 64 + c * 16 + L) * 32 + quad * 8];
#pragma unroll
    for (int r = 0; r < 4; r++)
#pragma unroll
      for (int c = 0; c < 4; c++)
        acc[r][c] = __builtin_amdgcn_mfma_f32_16x16x32_bf16(af[r], bf[c],
                                                            acc[r][c], 0, 0, 0);
    __syncthreads();
  }

  const int mbase = m0 + wm * 64;
  const int nbase = n0 + wn * 64;
#pragma unroll
  for (int c = 0; c < 4; c++) {
    const int n = nbase + c * 16 + L;
    const int h = n / 192;
    const int t = (n % 192) / 64;  // 0=Q 1=K 2=V, uniform across the frag
    const int d = n & 63;
    const float bv = bias[n];
#pragma unroll
    for (int r = 0; r < 4; r++) {
      const int mrow = mbase + r * 16 + quad * 4;
      const int b = mrow >> 11;     // / 2048
      const int s = mrow & 2047;
      if (t == 2) {
        alignas(8) __hip_bfloat16 t4[4];
#pragma unroll
        for (int g = 0; g < 4; g++) t4[g] = __float2bfloat16(acc[r][c][g] + bv);
        *(ushort4*)&vto[((size_t)((b * NH + h) * HDIM + d)) * S_LEN + s] =
            *(const ushort4*)t4;
      } else if (t == 0) {
#pragma unroll
        for (int g = 0; g < 4; g++)
          qo[((size_t)((b * NH + h) * S_LEN) + s + g) * HDIM + d] =
              __float2bfloat16((acc[r][c][g] + bv) * 0.125f);
      } else {
#pragma unroll
        for (int g = 0; g < 4; g++)
          ko[((size_t)((b * NH + h) * S_LEN) + s + g) * HDIM + d] =
              __float2bfloat16(acc[r][c][g] + bv);
      }
    }
  }
}

// ---------------- flash attention (causal) ----------------
// grid: (S/64, B*H). 4 waves; wave w owns 16 q-rows. K/V tiles of 32.
__global__ __launch_bounds__(256, 2) void flash_attn_kernel(
    const __hip_bfloat16* __restrict__ q,
    const __hip_bfloat16* __restrict__ k,
    const __hip_bfloat16* __restrict__ vt,
    __hip_bfloat16* __restrict__ attn) {
  __shared__ __hip_bfloat16 Qs[64 * 72];   // pad 72 to break stride-128B banks
  __shared__ __hip_bfloat16 Ks[32 * 72];
  __shared__ __hip_bfloat16 Vs[64 * 40];   // V^T tile [d][k], pad 40
  __shared__ __hip_bfloat16 Ps[4][16 * 32];
  const int tid = threadIdx.x;
  const int wave = tid >> 6, lane = tid & 63;
  const int L = lane & 15, quad = lane >> 4;
  const int qb = blockIdx.x * 64;
  const int bh = blockIdx.y;
  const __hip_bfloat16* Qg = q + (size_t)bh * S_LEN * HDIM;
  const __hip_bfloat16* Kg = k + (size_t)bh * S_LEN * HDIM;
  const __hip_bfloat16* Vg = vt + (size_t)bh * HDIM * S_LEN;

  // stage Q (64x64)
#pragma unroll
  for (int p = 0; p < 2; p++) {
    int row = p * 32 + (tid >> 3);
    int c8 = (tid & 7) * 8;
    *(uint4*)&Qs[row * 72 + c8] = *(const uint4*)&Qg[(size_t)(qb + row) * HDIM + c8];
  }
  __syncthreads();
  bf16x8 qf[2];
#pragma unroll
  for (int i = 0; i < 2; i++)
    qf[i] = *(const bf16x8*)&Qs[(wave * 16 + L) * 72 + i * 32 + quad * 8];

  float m_i[4], l_i[4];
  f32x4 o[4] = {};
#pragma unroll
  for (int g = 0; g < 4; g++) { m_i[g] = -1e30f; l_i[g] = 0.f; }

  const int wqb = qb + wave * 16;
  const int nkt = (qb + 64) >> 5;
  for (int kt = 0; kt < nkt; kt++) {
    const int k0 = kt * 32;
    {  // stage K (32x64) and V^T (64x32)
      int row = tid >> 3, c8 = (tid & 7) * 8;
      *(uint4*)&Ks[row * 72 + c8] = *(const uint4*)&Kg[(size_t)(k0 + row) * HDIM + c8];
      int vr = tid >> 2, vc = (tid & 3) * 8;
      *(uint4*)&Vs[vr * 40 + vc] = *(const uint4*)&Vg[(size_t)vr * S_LEN + k0 + vc];
    }
    __syncthreads();
    if (k0 <= wqb + 15) {  // wave-uniform: at least one unmasked column
      f32x4 sc[2] = {};
#pragma unroll
      for (int sub = 0; sub < 2; sub++)
#pragma unroll
        for (int i = 0; i < 2; i++) {
          bf16x8 kf = *(const bf16x8*)&Ks[(sub * 16 + L) * 72 + i * 32 + quad * 8];
          sc[sub] = __builtin_amdgcn_mfma_f32_16x16x32_bf16(qf[i], kf, sc[sub], 0, 0, 0);
        }
      // causal mask: C/D layout col = L, row = quad*4+g
#pragma unroll
      for (int sub = 0; sub < 2; sub++) {
        int kg = k0 + sub * 16 + L;
#pragma unroll
        for (int g = 0; g < 4; g++) {
          int qg = wqb + quad * 4 + g;
          if (kg > qg) sc[sub][g] = -1e30f;
        }
      }
      float mx[4], al[4], rs[4];
#pragma unroll
      for (int g = 0; g < 4; g++) mx[g] = fmaxf(sc[0][g], sc[1][g]);
#pragma unroll
      for (int off = 8; off > 0; off >>= 1)
#pragma unroll
        for (int g = 0; g < 4; g++)
          mx[g] = fmaxf(mx[g], __shfl_xor(mx[g], off, 64));
#pragma unroll
      for (int g = 0; g < 4; g++) {
        float mn = fmaxf(m_i[g], mx[g]);
        al[g] = __expf(m_i[g] - mn);
        m_i[g] = mn;
      }
      f32x4 pr[2];
#pragma unroll
      for (int sub = 0; sub < 2; sub++)
#pragma unroll
        for (int g = 0; g < 4; g++)
          pr[sub][g] = __expf(sc[sub][g] - m_i[g]);
#pragma unroll
      for (int g = 0; g < 4; g++) rs[g] = pr[0][g] + pr[1][g];
#pragma unroll
      for (int off = 8; off > 0; off >>= 1)
#pragma unroll
        for (int g = 0; g < 4; g++)
          rs[g] += __shfl_xor(rs[g], off, 64);
#pragma unroll
      for (int g = 0; g < 4; g++) l_i[g] = l_i[g] * al[g] + rs[g];
#pragma unroll
      for (int dg = 0; dg < 4; dg++)
#pragma unroll
        for (int g = 0; g < 4; g++) o[dg][g] *= al[g];
      // P: C-layout -> LDS -> A-layout (m120 recipe), wave-private region
      __hip_bfloat16* ps = &Ps[wave][0];
#pragma unroll
      for (int sub = 0; sub < 2; sub++)
#pragma unroll
        for (int g = 0; g < 4; g++)
          ps[(quad * 4 + g) * 32 + sub * 16 + L] = __float2bfloat16(pr[sub][g]);
      __asm__ volatile("s_waitcnt lgkmcnt(0)" ::: "memory");
      bf16x8 pf = *(const bf16x8*)&ps[L * 32 + quad * 8];
#pragma unroll
      for (int dg = 0; dg < 4; dg++) {
        bf16x8 vf = *(const bf16x8*)&Vs[(dg * 16 + L) * 40 + quad * 8];
        o[dg] = __builtin_amdgcn_mfma_f32_16x16x32_bf16(pf, vf, o[dg], 0, 0, 0);
      }
    }
    __syncthreads();
  }
  const int b = bh >> 4, h = bh & 15;
#pragma unroll
  for (int dg = 0; dg < 4; dg++)
#pragma unroll
    for (int g = 0; g < 4; g++) {
      int qg = wqb + quad * 4 + g;
      float v = o[dg][g] / l_i[g];
      attn[((size_t)(b * S_LEN + qg)) * 1024 + h * 64 + dg * 16 + L] =
          __float2bfloat16(v);
    }
}

// ---------------- out GEMM: (4096,1024)x(1024,1024)+bias -> fp32 ----------------
__global__ __launch_bounds__(256, 2) void out_gemm_kernel(
    const __hip_bfloat16* __restrict__ A,
    const __hip_bfloat16* __restrict__ Bt,
    const float* __restrict__ bias,
    float* __restrict__ out) {
  __shared__ __hip_bfloat16 As[128 * 32];
  __shared__ __hip_bfloat16 Bs[128 * 32];
  const int tid = threadIdx.x;
  const int wave = tid >> 6, lane = tid & 63;
  const int L = lane & 15, quad = lane >> 4;
  const int wm = wave >> 1, wn = wave & 1;
  const int m0 = blockIdx.y * 128, n0 = blockIdx.x * 128;

  f32x4 acc[4][4] = {};

  const int srow = tid >> 2;
  const int scol = (tid & 3) * 8;
  const __hip_bfloat16* ag = A + (size_t)(m0 + srow) * KDIM + scol;
  const __hip_bfloat16* bg = Bt + (size_t)(n0 + srow) * KDIM + scol;
  char* asd = (char*)As + wave * 1024;
  char* bsd = (char*)Bs + wave * 1024;

  for (int kt = 0; kt < KDIM; kt += 32) {
    async16(ag + kt, asd);
    async16(ag + kt + (size_t)64 * KDIM, asd + 4096);
    async16(bg + kt, bsd);
    async16(bg + kt + (size_t)64 * KDIM, bsd + 4096);
    __syncthreads();
    bf16x8 af[4], bf[4];
#pragma unroll
    for (int r = 0; r < 4; r++)
      af[r] = *(const bf16x8*)&As[(wm * 64 + r * 16 + L) * 32 + quad * 8];
#pragma unroll
    for (int c = 0; c < 4; c++)
      bf[c] = *(const bf16x8*)&Bs[(wn * 64 + c * 16 + L) * 32 + quad * 8];
#pragma unroll
    for (int r = 0; r < 4; r++)
#pragma unroll
      for (int c = 0; c < 4; c++)
        acc[r][c] = __builtin_amdgcn_mfma_f32_16x16x32_bf16(af[r], bf[c],
                                                            acc[r][c], 0, 0, 0);
    __syncthreads();
  }

#pragma unroll
  for (int c = 0; c < 4; c++) {
    const int n = n0 + wn * 64 + c * 16 + L;
    const float bv = bias[n];
#pragma unroll
    for (int r = 0; r < 4; r++) {
      const int mrow = m0 + wm * 64 + r * 16 + quad * 4;
#pragma unroll
      for (int g = 0; g < 4; g++)
        out[(size_t)(mrow + g) * 1024 + n] = acc[r][c][g] + bv;
    }
  }
}

extern "C" void kernel_launch(void* const* d_in, const int* in_sizes, int n_in,
                              void* d_out, int out_size, void* d_ws, size_t ws_size,
                              hipStream_t stream) {
  const float* x     = (const float*)d_in[0];
  const float* w_qkv = (const float*)d_in[1];
  const float* b_qkv = (const float*)d_in[2];
  const float* w_out = (const float*)d_in[3];
  const float* b_out = (const float*)d_in[4];
  float* out = (float*)d_out;

  __hip_bfloat16* ws = (__hip_bfloat16*)d_ws;
  __hip_bfloat16* xb   = ws;                          // 4096x1024
  __hip_bfloat16* wqkt = xb   + (size_t)4194304;      // 3072x1024 (w_qkv^T)
  __hip_bfloat16* wot  = wqkt + (size_t)3145728;      // 1024x1024 (w_out^T)
  __hip_bfloat16* qb   = wot  + (size_t)1048576;      // [2][16][2048][64]
  __hip_bfloat16* kb   = qb   + (size_t)4194304;
  __hip_bfloat16* vtb  = kb   + (size_t)4194304;      // [2][16][64][2048]
  __hip_bfloat16* attn = vtb  + (size_t)4194304;      // [2][2048][1024]

  cast_bf16_kernel<<<2048, 256, 0, stream>>>(x, xb, MTOK * KDIM);
  transpose_cast_kernel<<<dim3(NQKV / 64, KDIM / 64), 256, 0, stream>>>(
      w_qkv, wqkt, KDIM, NQKV);
  transpose_cast_kernel<<<dim3(KDIM / 64, KDIM / 64), 256, 0, stream>>>(
      w_out, wot, KDIM, KDIM);
  qkv_gemm_kernel<<<dim3(NQKV / 128, MTOK / 128), 256, 0, stream>>>(
      xb, wqkt, b_qkv, qb, kb, vtb);
  flash_attn_kernel<<<dim3(S_LEN / 64, 2 * NH), 256, 0, stream>>>(
      qb, kb, vtb, attn);
  out_gemm_kernel<<<dim3(KDIM / 128, MTOK / 128), 256, 0, stream>>>(
      attn, wot, b_out, out);
}

// Round 2
// 244.020 us; speedup vs baseline: 1.2675x; 1.2675x over previous
//
#include <hip/hip_runtime.h>
#include <hip/hip_bf16.h>
#include <stdint.h>

typedef __attribute__((ext_vector_type(8))) short bf16x8;
typedef __attribute__((ext_vector_type(4))) float f32x4;

#define DEVFN static __device__ __forceinline__

typedef const __attribute__((address_space(1))) void* gas_ptr;
typedef __attribute__((address_space(3))) void* las_ptr;

// async global->LDS, 16B per lane; LDS dest = wave-uniform base + lane*16
DEVFN void async16(const void* g, void* l) {
  __builtin_amdgcn_global_load_lds((gas_ptr)g, (las_ptr)l, 16, 0, 0);
}

#define S_LEN 2048
#define NH    16
#define HDIM  64
#define KDIM  1024
#define NQKV  3072
#define MTOK  4096

// softmax scale 1/8 with log2(e) folded in (we use exp2 = native v_exp_f32)
#define QK_SCALE 0.1803368801111244f

// ---------------- flat cast fp32 -> bf16 ----------------
__global__ void cast_bf16_kernel(const float* __restrict__ in,
                                 __hip_bfloat16* __restrict__ out, int n) {
  int i = (blockIdx.x * 256 + threadIdx.x) * 8;
  if (i >= n) return;
  float4 a = *(const float4*)(in + i);
  float4 b = *(const float4*)(in + i + 4);
  alignas(16) __hip_bfloat16 t[8] = {
      __float2bfloat16(a.x), __float2bfloat16(a.y),
      __float2bfloat16(a.z), __float2bfloat16(a.w),
      __float2bfloat16(b.x), __float2bfloat16(b.y),
      __float2bfloat16(b.z), __float2bfloat16(b.w)};
  *(uint4*)(out + i) = *(const uint4*)t;
}

// ------------- transpose (K,N) fp32 -> (N,K) bf16 -------------
__global__ __launch_bounds__(256) void transpose_cast_kernel(
    const float* __restrict__ in, __hip_bfloat16* __restrict__ out,
    int K, int N) {
  __shared__ float T[64][65];
  const int tid = threadIdx.x;
  const int n0 = blockIdx.x * 64, k0 = blockIdx.y * 64;
#pragma unroll
  for (int it = 0; it < 4; it++) {
    int r = it * 16 + (tid >> 4);
    int c = (tid & 15) * 4;
    float4 v = *(const float4*)&in[(size_t)(k0 + r) * N + n0 + c];
    T[r][c + 0] = v.x; T[r][c + 1] = v.y; T[r][c + 2] = v.z; T[r][c + 3] = v.w;
  }
  __syncthreads();
#pragma unroll
  for (int it = 0; it < 4; it++) {
    int rn = it * 16 + (tid >> 4);
    int ck = (tid & 15) * 4;
    alignas(8) __hip_bfloat16 t4[4];
#pragma unroll
    for (int j = 0; j < 4; j++) t4[j] = __float2bfloat16(T[ck + j][rn]);
    *(ushort4*)&out[(size_t)(n0 + rn) * K + k0 + ck] = *(const ushort4*)t4;
  }
}

// ---------------- QKV GEMM: (4096,1024)x(1024,3072)+bias ----------------
// Q -> q[b][h][s][d] * QK_SCALE (pre-scaled), K -> k[b][h][s][d], V -> vt[b][h][d][s]
__global__ __launch_bounds__(256, 2) void qkv_gemm_kernel(
    const __hip_bfloat16* __restrict__ A,
    const __hip_bfloat16* __restrict__ Bt,
    const float* __restrict__ bias,
    __hip_bfloat16* __restrict__ qo,
    __hip_bfloat16* __restrict__ ko,
    __hip_bfloat16* __restrict__ vto) {
  __shared__ __hip_bfloat16 As[128 * 32];
  __shared__ __hip_bfloat16 Bs[128 * 32];
  const int tid = threadIdx.x;
  const int wave = tid >> 6, lane = tid & 63;
  const int L = lane & 15, quad = lane >> 4;
  const int wm = wave >> 1, wn = wave & 1;
  const int m0 = blockIdx.y * 128, n0 = blockIdx.x * 128;

  f32x4 acc[4][4] = {};

  const int srow = tid >> 2;
  const int scol = (tid & 3) * 8;
  const __hip_bfloat16* ag = A + (size_t)(m0 + srow) * KDIM + scol;
  const __hip_bfloat16* bg = Bt + (size_t)(n0 + srow) * KDIM + scol;
  char* asd = (char*)As + wave * 1024;
  char* bsd = (char*)Bs + wave * 1024;

  for (int kt = 0; kt < KDIM; kt += 32) {
    async16(ag + kt, asd);
    async16(ag + kt + (size_t)64 * KDIM, asd + 4096);
    async16(bg + kt, bsd);
    async16(bg + kt + (size_t)64 * KDIM, bsd + 4096);
    __syncthreads();
    bf16x8 af[4], bf[4];
#pragma unroll
    for (int r = 0; r < 4; r++)
      af[r] = *(const bf16x8*)&As[(wm * 64 + r * 16 + L) * 32 + quad * 8];
#pragma unroll
    for (int c = 0; c < 4; c++)
      bf[c] = *(const bf16x8*)&Bs[(wn * 64 + c * 16 + L) * 32 + quad * 8];
#pragma unroll
    for (int r = 0; r < 4; r++)
#pragma unroll
      for (int c = 0; c < 4; c++)
        acc[r][c] = __builtin_amdgcn_mfma_f32_16x16x32_bf16(af[r], bf[c],
                                                            acc[r][c], 0, 0, 0);
    __syncthreads();
  }

  const int mbase = m0 + wm * 64;
  const int nbase = n0 + wn * 64;
#pragma unroll
  for (int c = 0; c < 4; c++) {
    const int n = nbase + c * 16 + L;
    const int h = n / 192;
    const int t = (n % 192) / 64;  // 0=Q 1=K 2=V, uniform across the frag
    const int d = n & 63;
    const float bv = bias[n];
#pragma unroll
    for (int r = 0; r < 4; r++) {
      const int mrow = mbase + r * 16 + quad * 4;
      const int b = mrow >> 11;
      const int s = mrow & 2047;
      if (t == 2) {
        alignas(8) __hip_bfloat16 t4[4];
#pragma unroll
        for (int g = 0; g < 4; g++) t4[g] = __float2bfloat16(acc[r][c][g] + bv);
        *(ushort4*)&vto[((size_t)((b * NH + h) * HDIM + d)) * S_LEN + s] =
            *(const ushort4*)t4;
      } else if (t == 0) {
#pragma unroll
        for (int g = 0; g < 4; g++)
          qo[((size_t)((b * NH + h) * S_LEN) + s + g) * HDIM + d] =
              __float2bfloat16((acc[r][c][g] + bv) * QK_SCALE);
      } else {
#pragma unroll
        for (int g = 0; g < 4; g++)
          ko[((size_t)((b * NH + h) * S_LEN) + s + g) * HDIM + d] =
              __float2bfloat16(acc[r][c][g] + bv);
      }
    }
  }
}

// ---------------- flash attention (causal), S^T formulation ----------------
// grid: (S/128, B*H). 4 waves; wave w owns interleaved 16-row frags:
//   r=0: rows qb+w*16..+15,  r=1: rows qb+64+w*16..+15   (balanced diag masking)
// K-tile = 64. Computes S^T = K*Q^T so softmax row-axis = C/D col (lane L):
//   reduction = in-register over 16 + xor16 + xor32 (2 shuffles).
// P transpose: 4 consecutive kk per acc reg -> ds_write_b64, read back b128.
__global__ __launch_bounds__(256, 2) void flash_attn_kernel(
    const __hip_bfloat16* __restrict__ q,
    const __hip_bfloat16* __restrict__ k,
    const __hip_bfloat16* __restrict__ vt,
    __hip_bfloat16* __restrict__ attn) {
  __shared__ __hip_bfloat16 Ks[64 * 72];       // [kk][d], pad 72
  __shared__ __hip_bfloat16 Vs[64 * 72];       // [d][kk], pad 72
  __shared__ __hip_bfloat16 Ps[4][32 * 72];    // per-wave P [q][kk]
  const int tid = threadIdx.x;
  const int wave = tid >> 6, lane = tid & 63;
  const int L = lane & 15, quad = lane >> 4;
  const int qb = ((int)gridDim.x - 1 - (int)blockIdx.x) * 128;  // big blocks first
  const int bh = blockIdx.y;
  const __hip_bfloat16* Qg = q + (size_t)bh * S_LEN * HDIM;
  const __hip_bfloat16* Kg = k + (size_t)bh * S_LEN * HDIM;
  const __hip_bfloat16* Vg = vt + (size_t)bh * HDIM * S_LEN;

  int wq[2];
  wq[0] = qb + wave * 16;
  wq[1] = qb + 64 + wave * 16;

  // Q fragments straight from global (B-operand: rows q, k = d)
  bf16x8 qf[2][2];
#pragma unroll
  for (int r = 0; r < 2; r++)
#pragma unroll
    for (int kd = 0; kd < 2; kd++)
      qf[r][kd] =
          *(const bf16x8*)&Qg[(size_t)(wq[r] + L) * HDIM + kd * 32 + quad * 8];

  float m_i[2] = {-1e30f, -1e30f};
  float l_i[2] = {0.f, 0.f};
  f32x4 o[2][4] = {};  // o[r][dsub]: row(quad*4+g)=q, col(L)=d

  const int srow = tid >> 3;       // 0..31
  const int scol = (tid & 7) * 8;  // 0..56
  uint4 kreg[2], vreg[2];
#pragma unroll
  for (int p = 0; p < 2; p++) {  // preload tile 0
    kreg[p] = *(const uint4*)&Kg[(size_t)(p * 32 + srow) * HDIM + scol];
    vreg[p] = *(const uint4*)&Vg[(size_t)(p * 32 + srow) * S_LEN + scol];
  }

  const int nkt = (qb + 128) >> 6;
  for (int kt = 0; kt < nkt; kt++) {
    const int k0 = kt * 64;
    __syncthreads();  // previous tile's LDS reads done
#pragma unroll
    for (int p = 0; p < 2; p++) {
      *(uint4*)&Ks[(p * 32 + srow) * 72 + scol] = kreg[p];
      *(uint4*)&Vs[(p * 32 + srow) * 72 + scol] = vreg[p];
    }
    __syncthreads();  // staging visible (drains everything anyway)
    if (kt + 1 < nkt) {
      const int k1 = k0 + 64;
#pragma unroll
      for (int p = 0; p < 2; p++) {  // in flight across the whole compute
        kreg[p] = *(const uint4*)&Kg[(size_t)(k1 + p * 32 + srow) * HDIM + scol];
        vreg[p] = *(const uint4*)&Vg[(size_t)(p * 32 + srow) * S_LEN + k1 + scol];
      }
    }

    // K frags (A-operand: rows kk, k = d) and V frags (B-operand: rows d, k = kk)
    bf16x8 kfr[4][2], vfr[4][2];
#pragma unroll
    for (int ks = 0; ks < 4; ks++)
#pragma unroll
      for (int kd = 0; kd < 2; kd++)
        kfr[ks][kd] = *(const bf16x8*)&Ks[(ks * 16 + L) * 72 + kd * 32 + quad * 8];
#pragma unroll
    for (int dsb = 0; dsb < 4; dsb++)
#pragma unroll
      for (int kf = 0; kf < 2; kf++)
        vfr[dsb][kf] = *(const bf16x8*)&Vs[(dsb * 16 + L) * 72 + kf * 32 + quad * 8];

#pragma unroll
    for (int r = 0; r < 2; r++) {
      if (k0 > wq[r] + 15) continue;  // wave-uniform: fully masked
      // S^T tile: st[ks] rows kk = k0+ks*16+quad*4+g, col q = wq[r]+L
      f32x4 st[4] = {};
#pragma unroll
      for (int ks = 0; ks < 4; ks++)
#pragma unroll
        for (int kd = 0; kd < 2; kd++)
          st[ks] = __builtin_amdgcn_mfma_f32_16x16x32_bf16(
              kfr[ks][kd], qf[r][kd], st[ks], 0, 0, 0);
      if (k0 + 63 > wq[r]) {  // diagonal tile: apply causal mask
        const int qrow = wq[r] + L;
#pragma unroll
        for (int ks = 0; ks < 4; ks++)
#pragma unroll
          for (int g = 0; g < 4; g++) {
            int kk = k0 + ks * 16 + quad * 4 + g;
            if (kk > qrow) st[ks][g] = -1e30f;
          }
      }
      // row max over kk for q = L: in-register 16 + 2 shuffles
      float mx = -1e30f;
#pragma unroll
      for (int ks = 0; ks < 4; ks++)
        mx = fmaxf(mx, fmaxf(fmaxf(st[ks][0], st[ks][1]),
                             fmaxf(st[ks][2], st[ks][3])));
      mx = fmaxf(mx, __shfl_xor(mx, 16, 64));
      mx = fmaxf(mx, __shfl_xor(mx, 32, 64));
      const float mnew = fmaxf(m_i[r], mx);
      const float alpha = __builtin_amdgcn_exp2f(m_i[r] - mnew);
      m_i[r] = mnew;
      float rs = 0.f;
#pragma unroll
      for (int ks = 0; ks < 4; ks++) {
        f32x4 pv;
#pragma unroll
        for (int g = 0; g < 4; g++) {
          pv[g] = __builtin_amdgcn_exp2f(st[ks][g] - mnew);
          rs += pv[g];
        }
        alignas(8) __hip_bfloat16 t4[4];
#pragma unroll
        for (int g = 0; g < 4; g++) t4[g] = __float2bfloat16(pv[g]);
        // P[q][kk]: 4 consecutive kk for one q -> one b64 write
        *(ushort4*)&Ps[wave][(r * 16 + L) * 72 + ks * 16 + quad * 4] =
            *(const ushort4*)t4;
      }
      rs += __shfl_xor(rs, 16, 64);
      rs += __shfl_xor(rs, 32, 64);
      l_i[r] = l_i[r] * alpha + rs;
      // rescale O rows (q = quad*4+g): broadcast alpha from lane quad*4+g
#pragma unroll
      for (int g = 0; g < 4; g++) {
        const float ag = __shfl(alpha, quad * 4 + g, 64);
#pragma unroll
        for (int dsb = 0; dsb < 4; dsb++) o[r][dsb][g] *= ag;
      }
      __asm__ volatile("s_waitcnt lgkmcnt(0)" ::: "memory");  // P writes done (wave-private)
      bf16x8 pf[2];
#pragma unroll
      for (int kf = 0; kf < 2; kf++)
        pf[kf] = *(const bf16x8*)&Ps[wave][(r * 16 + L) * 72 + kf * 32 + quad * 8];
#pragma unroll
      for (int dsb = 0; dsb < 4; dsb++)
#pragma unroll
        for (int kf = 0; kf < 2; kf++)
          o[r][dsb] = __builtin_amdgcn_mfma_f32_16x16x32_bf16(
              pf[kf], vfr[dsb][kf], o[r][dsb], 0, 0, 0);
    }
  }

  const int b = bh >> 4, h = bh & 15;
#pragma unroll
  for (int r = 0; r < 2; r++) {
    float linv[4];
#pragma unroll
    for (int g = 0; g < 4; g++)
      linv[g] = 1.0f / __shfl(l_i[r], quad * 4 + g, 64);
#pragma unroll
    for (int dsb = 0; dsb < 4; dsb++)
#pragma unroll
      for (int g = 0; g < 4; g++) {
        const int qg = wq[r] + quad * 4 + g;
        attn[((size_t)(b * S_LEN + qg)) * 1024 + h * 64 + dsb * 16 + L] =
            __float2bfloat16(o[r][dsb][g] * linv[g]);
      }
  }
}

// ---------------- out GEMM: (4096,1024)x(1024,1024)+bias -> fp32 ----------------
__global__ __launch_bounds__(256, 2) void out_gemm_kernel(
    const __hip_bfloat16* __restrict__ A,
    const __hip_bfloat16* __restrict__ Bt,
    const float* __restrict__ bias,
    float* __restrict__ out) {
  __shared__ __hip_bfloat16 As[128 * 32];
  __shared__ __hip_bfloat16 Bs[128 * 32];
  const int tid = threadIdx.x;
  const int wave = tid >> 6, lane = tid & 63;
  const int L = lane & 15, quad = lane >> 4;
  const int wm = wave >> 1, wn = wave & 1;
  const int m0 = blockIdx.y * 128, n0 = blockIdx.x * 128;

  f32x4 acc[4][4] = {};

  const int srow = tid >> 2;
  const int scol = (tid & 3) * 8;
  const __hip_bfloat16* ag = A + (size_t)(m0 + srow) * KDIM + scol;
  const __hip_bfloat16* bg = Bt + (size_t)(n0 + srow) * KDIM + scol;
  char* asd = (char*)As + wave * 1024;
  char* bsd = (char*)Bs + wave * 1024;

  for (int kt = 0; kt < KDIM; kt += 32) {
    async16(ag + kt, asd);
    async16(ag + kt + (size_t)64 * KDIM, asd + 4096);
    async16(bg + kt, bsd);
    async16(bg + kt + (size_t)64 * KDIM, bsd + 4096);
    __syncthreads();
    bf16x8 af[4], bf[4];
#pragma unroll
    for (int r = 0; r < 4; r++)
      af[r] = *(const bf16x8*)&As[(wm * 64 + r * 16 + L) * 32 + quad * 8];
#pragma unroll
    for (int c = 0; c < 4; c++)
      bf[c] = *(const bf16x8*)&Bs[(wn * 64 + c * 16 + L) * 32 + quad * 8];
#pragma unroll
    for (int r = 0; r < 4; r++)
#pragma unroll
      for (int c = 0; c < 4; c++)
        acc[r][c] = __builtin_amdgcn_mfma_f32_16x16x32_bf16(af[r], bf[c],
                                                            acc[r][c], 0, 0, 0);
    __syncthreads();
  }

#pragma unroll
  for (int c = 0; c < 4; c++) {
    const int n = n0 + wn * 64 + c * 16 + L;
    const float bv = bias[n];
#pragma unroll
    for (int r = 0; r < 4; r++) {
      const int mrow = m0 + wm * 64 + r * 16 + quad * 4;
#pragma unroll
      for (int g = 0; g < 4; g++)
        out[(size_t)(mrow + g) * 1024 + n] = acc[r][c][g] + bv;
    }
  }
}

extern "C" void kernel_launch(void* const* d_in, const int* in_sizes, int n_in,
                              void* d_out, int out_size, void* d_ws, size_t ws_size,
                              hipStream_t stream) {
  const float* x     = (const float*)d_in[0];
  const float* w_qkv = (const float*)d_in[1];
  const float* b_qkv = (const float*)d_in[2];
  const float* w_out = (const float*)d_in[3];
  const float* b_out = (const float*)d_in[4];
  float* out = (float*)d_out;

  __hip_bfloat16* ws = (__hip_bfloat16*)d_ws;
  __hip_bfloat16* xb   = ws;                          // 4096x1024
  __hip_bfloat16* wqkt = xb   + (size_t)4194304;      // 3072x1024 (w_qkv^T)
  __hip_bfloat16* wot  = wqkt + (size_t)3145728;      // 1024x1024 (w_out^T)
  __hip_bfloat16* qb   = wot  + (size_t)1048576;      // [2][16][2048][64]
  __hip_bfloat16* kb   = qb   + (size_t)4194304;
  __hip_bfloat16* vtb  = kb   + (size_t)4194304;      // [2][16][64][2048]
  __hip_bfloat16* attn = vtb  + (size_t)4194304;      // [2][2048][1024]

  cast_bf16_kernel<<<2048, 256, 0, stream>>>(x, xb, MTOK * KDIM);
  transpose_cast_kernel<<<dim3(NQKV / 64, KDIM / 64), 256, 0, stream>>>(
      w_qkv, wqkt, KDIM, NQKV);
  transpose_cast_kernel<<<dim3(KDIM / 64, KDIM / 64), 256, 0, stream>>>(
      w_out, wot, KDIM, KDIM);
  qkv_gemm_kernel<<<dim3(NQKV / 128, MTOK / 128), 256, 0, stream>>>(
      xb, wqkt, b_qkv, qb, kb, vtb);
  flash_attn_kernel<<<dim3(S_LEN / 128, 2 * NH), 256, 0, stream>>>(
      qb, kb, vtb, attn);
  out_gemm_kernel<<<dim3(KDIM / 128, MTOK / 128), 256, 0, stream>>>(
      attn, wot, b_out, out);
}